// Round 1
// baseline (1318.371 us; speedup 1.0000x reference)
//
#include <hip/hip_runtime.h>
#include <math.h>

#define B_   16
#define N_   6
#define P_   70000
#define H_   112
#define W_   200
#define HW_  (H_ * W_)
#define BSN_ (B_ * N_)

// ---------- shared math helpers (identical codegen in both passes) ----------

// dot of matrix row r[0..3] with [x,y,z,1], ascending-j fma chain (mirrors
// XLA's sequential reduction for einsum('mij,mpj->mpi'))
__device__ __forceinline__ float rdot(const float r[4], float x, float y, float z) {
    float s = r[0] * x;
    s = fmaf(r[1], y, s);
    s = fmaf(r[2], z, s);
    s = s + r[3];
    return s;
}

// general 4x4 inverse via adjugate (exact for the setup's view matrix,
// matching jnp.linalg.inv's LU result bit-for-bit on these exact values)
__device__ __forceinline__ void inv4(const float* m, float* o) {
    float inv[16];
    inv[0]  =  m[5]*m[10]*m[15] - m[5]*m[11]*m[14] - m[9]*m[6]*m[15] + m[9]*m[7]*m[14] + m[13]*m[6]*m[11] - m[13]*m[7]*m[10];
    inv[4]  = -m[4]*m[10]*m[15] + m[4]*m[11]*m[14] + m[8]*m[6]*m[15] - m[8]*m[7]*m[14] - m[12]*m[6]*m[11] + m[12]*m[7]*m[10];
    inv[8]  =  m[4]*m[9]*m[15]  - m[4]*m[11]*m[13] - m[8]*m[5]*m[15] + m[8]*m[7]*m[13] + m[12]*m[5]*m[11] - m[12]*m[7]*m[9];
    inv[12] = -m[4]*m[9]*m[14]  + m[4]*m[10]*m[13] + m[8]*m[5]*m[14] - m[8]*m[6]*m[13] - m[12]*m[5]*m[10] + m[12]*m[6]*m[9];
    inv[1]  = -m[1]*m[10]*m[15] + m[1]*m[11]*m[14] + m[9]*m[2]*m[15] - m[9]*m[3]*m[14] - m[13]*m[2]*m[11] + m[13]*m[3]*m[10];
    inv[5]  =  m[0]*m[10]*m[15] - m[0]*m[11]*m[14] - m[8]*m[2]*m[15] + m[8]*m[3]*m[14] + m[12]*m[2]*m[11] - m[12]*m[3]*m[10];
    inv[9]  = -m[0]*m[9]*m[15]  + m[0]*m[11]*m[13] + m[8]*m[1]*m[15] - m[8]*m[3]*m[13] - m[12]*m[1]*m[11] + m[12]*m[3]*m[9];
    inv[13] =  m[0]*m[9]*m[14]  - m[0]*m[10]*m[13] - m[8]*m[1]*m[14] + m[8]*m[2]*m[13] + m[12]*m[1]*m[10] - m[12]*m[2]*m[9];
    inv[2]  =  m[1]*m[6]*m[15]  - m[1]*m[7]*m[14]  - m[5]*m[2]*m[15] + m[5]*m[3]*m[14] + m[13]*m[2]*m[7]  - m[13]*m[3]*m[6];
    inv[6]  = -m[0]*m[6]*m[15]  + m[0]*m[7]*m[14]  + m[4]*m[2]*m[15] - m[4]*m[3]*m[14] - m[12]*m[2]*m[7]  + m[12]*m[3]*m[6];
    inv[10] =  m[0]*m[5]*m[15]  - m[0]*m[7]*m[13]  - m[4]*m[1]*m[15] + m[4]*m[3]*m[13] + m[12]*m[1]*m[7]  - m[12]*m[3]*m[5];
    inv[14] = -m[0]*m[5]*m[14]  + m[0]*m[6]*m[13]  + m[4]*m[1]*m[14] - m[4]*m[2]*m[13] - m[12]*m[1]*m[6]  + m[12]*m[2]*m[5];
    inv[3]  = -m[1]*m[6]*m[11]  + m[1]*m[7]*m[10]  + m[5]*m[2]*m[11] - m[5]*m[3]*m[10] - m[9]*m[2]*m[7]   + m[9]*m[3]*m[6];
    inv[7]  =  m[0]*m[6]*m[11]  - m[0]*m[7]*m[10]  - m[4]*m[2]*m[11] + m[4]*m[3]*m[10] + m[8]*m[2]*m[7]   - m[8]*m[3]*m[6];
    inv[11] = -m[0]*m[5]*m[11]  + m[0]*m[7]*m[9]   + m[4]*m[1]*m[11] - m[4]*m[3]*m[9]  - m[8]*m[1]*m[7]   + m[8]*m[3]*m[5];
    inv[15] =  m[0]*m[5]*m[10]  - m[0]*m[6]*m[9]   - m[4]*m[1]*m[10] + m[4]*m[2]*m[9]  + m[8]*m[1]*m[6]   - m[8]*m[2]*m[5];
    float det = m[0]*inv[0] + m[1]*inv[4] + m[2]*inv[8] + m[3]*inv[12];
    float rdet = 1.0f / det;
    for (int i = 0; i < 16; ++i) o[i] = inv[i] * rdet;
}

// Per-camera: Einv (rigid inverse, mirrors reference) and
// PFC = scale_intrinsics4(K, .25, .25) @ Einv (full 4x4 matmul, asc-k fma).
// Outputs: E2 = Einv row 2 (for z), PFC rows 0..2.
__device__ __forceinline__ void cam_mats(const float* Ein, const float* Kin,
                                         float E2[4], float PFC[3][4]) {
    float Einv[4][4];
    for (int i = 0; i < 3; ++i)
        for (int j = 0; j < 3; ++j)
            Einv[i][j] = Ein[j * 4 + i];          // R^T
    for (int i = 0; i < 3; ++i) {                  // -(R^T t), asc-j fma
        float s = Ein[0 * 4 + i] * Ein[0 * 4 + 3];
        s = fmaf(Ein[1 * 4 + i], Ein[1 * 4 + 3], s);
        s = fmaf(Ein[2 * 4 + i], Ein[2 * 4 + 3], s);
        Einv[i][3] = -s;
    }
    Einv[3][0] = Ein[12]; Einv[3][1] = Ein[13];
    Einv[3][2] = Ein[14]; Einv[3][3] = Ein[15];

    float K4[4][4] = {};                           // scaled intrinsics, 4x4
    K4[0][0] = Kin[0] * 0.25f;  K4[0][2] = Kin[2] * 0.25f;
    K4[1][1] = Kin[4] * 0.25f;  K4[1][2] = Kin[5] * 0.25f;
    K4[2][2] = 1.0f;            K4[3][3] = 1.0f;

    for (int i = 0; i < 3; ++i)
        for (int j = 0; j < 4; ++j) {              // K4 @ Einv, asc-k fma
            float s = K4[i][0] * Einv[0][j];
            s = fmaf(K4[i][1], Einv[1][j], s);
            s = fmaf(K4[i][2], Einv[2][j], s);
            s = fmaf(K4[i][3], Einv[3][j], s);
            PFC[i][j] = s;
        }
    for (int j = 0; j < 4; ++j) E2[j] = Einv[2][j];
}

// ---------- kernels ----------

__global__ __launch_bounds__(256) void k_init(int* __restrict__ w, int ntot) {
    int i = blockIdx.x * 256 + threadIdx.x;
    if (i < ntot) w[i] = -1;
}

// Pass 1: every (b,p) point scatters into all 6 cameras with atomicMax(p)
// -> max-p wins, matching XLA-CPU's sequential last-write-wins scatter.
__global__ __launch_bounds__(256) void k_scatter(
        const float4* __restrict__ pc, const float* __restrict__ extr,
        const float* __restrict__ intr, const float* __restrict__ view,
        int* __restrict__ win) {
    __shared__ float sV[4][4];
    __shared__ float sE2[N_][4];
    __shared__ float sP[N_][3][4];
    const int b = blockIdx.x;
    const int t = threadIdx.x;
    if (t == 0) {                                  // wave 0: Vinv
        float Vi[16];
        inv4(&view[b * 16], Vi);
        for (int i = 0; i < 4; ++i)
            for (int j = 0; j < 4; ++j) sV[i][j] = Vi[i * 4 + j];
    } else if (t >= 64 && t < 64 + N_) {           // wave 1: 6 cameras in parallel
        int n = t - 64;
        int m = b * N_ + n;
        float E2[4], PFC[3][4];
        cam_mats(&extr[m * 16], &intr[m * 9], E2, PFC);
        for (int j = 0; j < 4; ++j) sE2[n][j] = E2[j];
        for (int i = 0; i < 3; ++i)
            for (int j = 0; j < 4; ++j) sP[n][i][j] = PFC[i][j];
    }
    __syncthreads();
    const int p = blockIdx.y * 256 + t;
    if (p >= P_) return;
    float4 pt = pc[b * P_ + p];
    float lx = rdot(sV[0], pt.x, pt.y, pt.z);      // lidar -> view frame
    float ly = rdot(sV[1], pt.x, pt.y, pt.z);
    float lz = rdot(sV[2], pt.x, pt.y, pt.z);
    for (int n = 0; n < N_; ++n) {
        float px = rdot(sP[n][0], lx, ly, lz);
        float py = rdot(sP[n][1], lx, ly, lz);
        float pz = rdot(sP[n][2], lx, ly, lz);
        float denom = fmaxf(pz, 1e-6f);
        float x_ = px / denom;
        float y_ = py / denom;
        // all points scatter (invalid ones carry zeros in the reference)
        int ym = (int)fminf(fmaxf(y_, 0.0f), (float)(H_ - 1));
        int xm = (int)fminf(fmaxf(x_, 0.0f), (float)(W_ - 1));
        int m = b * N_ + n;
        atomicMax(&win[(m * 2) * HW_ + ym * W_ + xm], p);
    }
}

// Pass 2: per cell, recompute winning point's projection and emit both channels.
__global__ __launch_bounds__(256) void k_finalize(
        const float4* __restrict__ pc, const float* __restrict__ extr,
        const float* __restrict__ intr, const float* __restrict__ view,
        float* __restrict__ out, const int* __restrict__ bev_side_p) {
    __shared__ float sV[4][4];
    __shared__ float sE2[4];
    __shared__ float sP[3][4];
    const int m = blockIdx.x;
    const int b = m / N_;
    const int t = threadIdx.x;
    if (t == 0) {
        float Vi[16];
        inv4(&view[b * 16], Vi);
        for (int i = 0; i < 4; ++i)
            for (int j = 0; j < 4; ++j) sV[i][j] = Vi[i * 4 + j];
    } else if (t == 64) {
        float E2[4], PFC[3][4];
        cam_mats(&extr[m * 16], &intr[m * 9], E2, PFC);
        for (int j = 0; j < 4; ++j) sE2[j] = E2[j];
        for (int i = 0; i < 3; ++i)
            for (int j = 0; j < 4; ++j) sP[i][j] = PFC[i][j];
    }
    __syncthreads();
    const int r = blockIdx.y * 256 + t;
    if (r >= HW_) return;
    const int base0 = (m * 2) * HW_;
    const int w = ((const int*)out)[base0 + r];
    float depth = 0.0f, iluv = 0.0f;
    if (w >= 0) {
        const float bev_half = (float)bev_side_p[0] * 0.5f;   // 100.0
        const float clip_hi  = bev_half - 1.0f;               // 99.0
        float4 pt = pc[b * P_ + w];
        float lx = rdot(sV[0], pt.x, pt.y, pt.z);
        float ly = rdot(sV[1], pt.x, pt.y, pt.z);
        float lz = rdot(sV[2], pt.x, pt.y, pt.z);
        float z  = rdot(sE2,   lx, ly, lz);
        float px = rdot(sP[0], lx, ly, lz);
        float py = rdot(sP[1], lx, ly, lz);
        float pz = rdot(sP[2], lx, ly, lz);
        float denom = fmaxf(pz, 1e-6f);
        float x_ = px / denom;
        float y_ = py / denom;
        bool valid = (x_ > -0.5f) && (x_ < (float)W_ - 0.5f) &&
                     (y_ > -0.5f) && (y_ < (float)H_ - 0.5f) && (z > 0.0f);
        if (valid) {
            float d = fminf(fmaxf(pz, 0.0f), clip_hi);         // clip(normalizer,0,99)
            depth = d / bev_half;                              // /100
            float vi = fminf(fmaxf(pt.w, 0.0f), 255.0f);       // clip(ilu,0,255)
            iluv = log1pf(vi) / 5.545177444479562f;            // /log(256) as f32
        }
    }
    out[base0 + r]       = depth;   // overwrites winner slot
    out[base0 + HW_ + r] = iluv;
}

// ---------- launch ----------

extern "C" void kernel_launch(void* const* d_in, const int* in_sizes, int n_in,
                              void* d_out, int out_size, void* d_ws, size_t ws_size,
                              hipStream_t stream) {
    const float4* pc  = (const float4*)d_in[0];
    const float* extr = (const float*)d_in[1];
    const float* intr = (const float*)d_in[2];
    const float* view = (const float*)d_in[3];
    const int*   bev  = (const int*)d_in[4];
    float* out = (float*)d_out;

    k_init<<<dim3((out_size + 255) / 256), dim3(256), 0, stream>>>((int*)d_out, out_size);

    dim3 gc(B_, (P_ + 255) / 256);
    k_scatter<<<gc, dim3(256), 0, stream>>>(pc, extr, intr, view, (int*)d_out);

    dim3 gd(BSN_, (HW_ + 255) / 256);
    k_finalize<<<gd, dim3(256), 0, stream>>>(pc, extr, intr, view, out, bev);
}

// Round 2
// 69.194 us; speedup vs baseline: 19.0532x; 19.0532x over previous
//
#include <hip/hip_runtime.h>
#include <math.h>

#define B_    16
#define N_    6
#define P_    70000
#define H_    112
#define W_    200
#define HW_   (H_ * W_)
#define BSN_  (B_ * N_)
#define HALF_ 56                      // rows per block (H_/2)
#define CELLS_ (HALF_ * W_)           // 11200 cells, 44.8 KB LDS
#define THREADS_ 1024

// ---------- shared math helpers (identical codegen everywhere) ----------

// dot of matrix row r[0..3] with [x,y,z,1], ascending-j fma chain (mirrors
// XLA's sequential reduction for einsum('mij,mpj->mpi'))
__device__ __forceinline__ float rdot(const float r[4], float x, float y, float z) {
    float s = r[0] * x;
    s = fmaf(r[1], y, s);
    s = fmaf(r[2], z, s);
    s = s + r[3];
    return s;
}

// general 4x4 inverse via adjugate (matches jnp.linalg.inv bit-for-bit on
// the setup's view matrices — verified absmax 0.0 in round 1)
__device__ __forceinline__ void inv4(const float* m, float* o) {
    float inv[16];
    inv[0]  =  m[5]*m[10]*m[15] - m[5]*m[11]*m[14] - m[9]*m[6]*m[15] + m[9]*m[7]*m[14] + m[13]*m[6]*m[11] - m[13]*m[7]*m[10];
    inv[4]  = -m[4]*m[10]*m[15] + m[4]*m[11]*m[14] + m[8]*m[6]*m[15] - m[8]*m[7]*m[14] - m[12]*m[6]*m[11] + m[12]*m[7]*m[10];
    inv[8]  =  m[4]*m[9]*m[15]  - m[4]*m[11]*m[13] - m[8]*m[5]*m[15] + m[8]*m[7]*m[13] + m[12]*m[5]*m[11] - m[12]*m[7]*m[9];
    inv[12] = -m[4]*m[9]*m[14]  + m[4]*m[10]*m[13] + m[8]*m[5]*m[14] - m[8]*m[6]*m[13] - m[12]*m[5]*m[10] + m[12]*m[6]*m[9];
    inv[1]  = -m[1]*m[10]*m[15] + m[1]*m[11]*m[14] + m[9]*m[2]*m[15] - m[9]*m[3]*m[14] - m[13]*m[2]*m[11] + m[13]*m[3]*m[10];
    inv[5]  =  m[0]*m[10]*m[15] - m[0]*m[11]*m[14] - m[8]*m[2]*m[15] + m[8]*m[3]*m[14] + m[12]*m[2]*m[11] - m[12]*m[3]*m[10];
    inv[9]  = -m[0]*m[9]*m[15]  + m[0]*m[11]*m[13] + m[8]*m[1]*m[15] - m[8]*m[3]*m[13] - m[12]*m[1]*m[11] + m[12]*m[3]*m[9];
    inv[13] =  m[0]*m[9]*m[14]  - m[0]*m[10]*m[13] - m[8]*m[1]*m[14] + m[8]*m[2]*m[13] + m[12]*m[1]*m[10] - m[12]*m[2]*m[9];
    inv[2]  =  m[1]*m[6]*m[15]  - m[1]*m[7]*m[14]  - m[5]*m[2]*m[15] + m[5]*m[3]*m[14] + m[13]*m[2]*m[7]  - m[13]*m[3]*m[6];
    inv[6]  = -m[0]*m[6]*m[15]  + m[0]*m[7]*m[14]  + m[4]*m[2]*m[15] - m[4]*m[3]*m[14] - m[12]*m[2]*m[7]  + m[12]*m[3]*m[6];
    inv[10] =  m[0]*m[5]*m[15]  - m[0]*m[7]*m[13]  - m[4]*m[1]*m[15] + m[4]*m[3]*m[13] + m[12]*m[1]*m[7]  - m[12]*m[3]*m[5];
    inv[14] = -m[0]*m[5]*m[14]  + m[0]*m[6]*m[13]  + m[4]*m[1]*m[14] - m[4]*m[2]*m[13] - m[12]*m[1]*m[6]  + m[12]*m[2]*m[5];
    inv[3]  = -m[1]*m[6]*m[11]  + m[1]*m[7]*m[10]  + m[5]*m[2]*m[11] - m[5]*m[3]*m[10] - m[9]*m[2]*m[7]   + m[9]*m[3]*m[6];
    inv[7]  =  m[0]*m[6]*m[11]  - m[0]*m[7]*m[10]  - m[4]*m[2]*m[11] + m[4]*m[3]*m[10] + m[8]*m[2]*m[7]   - m[8]*m[3]*m[6];
    inv[11] = -m[0]*m[5]*m[11]  + m[0]*m[7]*m[9]   + m[4]*m[1]*m[11] - m[4]*m[3]*m[9]  - m[8]*m[1]*m[7]   + m[8]*m[3]*m[5];
    inv[15] =  m[0]*m[5]*m[10]  - m[0]*m[6]*m[9]   - m[4]*m[1]*m[10] + m[4]*m[2]*m[9]  + m[8]*m[1]*m[6]   - m[8]*m[2]*m[5];
    float det = m[0]*inv[0] + m[1]*inv[4] + m[2]*inv[8] + m[3]*inv[12];
    float rdet = 1.0f / det;
    for (int i = 0; i < 16; ++i) o[i] = inv[i] * rdet;
}

// Per-camera: Einv (rigid inverse) and PFC = scale_intrinsics4(K) @ Einv.
__device__ __forceinline__ void cam_mats(const float* Ein, const float* Kin,
                                         float E2[4], float PFC[3][4]) {
    float Einv[4][4];
    for (int i = 0; i < 3; ++i)
        for (int j = 0; j < 3; ++j)
            Einv[i][j] = Ein[j * 4 + i];          // R^T
    for (int i = 0; i < 3; ++i) {                  // -(R^T t), asc-j fma
        float s = Ein[0 * 4 + i] * Ein[0 * 4 + 3];
        s = fmaf(Ein[1 * 4 + i], Ein[1 * 4 + 3], s);
        s = fmaf(Ein[2 * 4 + i], Ein[2 * 4 + 3], s);
        Einv[i][3] = -s;
    }
    Einv[3][0] = Ein[12]; Einv[3][1] = Ein[13];
    Einv[3][2] = Ein[14]; Einv[3][3] = Ein[15];

    float K4[4][4] = {};
    K4[0][0] = Kin[0] * 0.25f;  K4[0][2] = Kin[2] * 0.25f;
    K4[1][1] = Kin[4] * 0.25f;  K4[1][2] = Kin[5] * 0.25f;
    K4[2][2] = 1.0f;            K4[3][3] = 1.0f;

    for (int i = 0; i < 3; ++i)
        for (int j = 0; j < 4; ++j) {
            float s = K4[i][0] * Einv[0][j];
            s = fmaf(K4[i][1], Einv[1][j], s);
            s = fmaf(K4[i][2], Einv[2][j], s);
            s = fmaf(K4[i][3], Einv[3][j], s);
            PFC[i][j] = s;
        }
    for (int j = 0; j < 4; ++j) E2[j] = Einv[2][j];
}

// ---------- fused kernel: one block per (camera m, row-half) ----------
// Phase A: LDS winner grid (max point index wins == XLA last-write-wins).
// Phase B: recompute winning point per cell and emit depth+ilu channels.

__global__ __launch_bounds__(THREADS_) void k_lidar_fused(
        const float4* __restrict__ pc, const float* __restrict__ extr,
        const float* __restrict__ intr, const float* __restrict__ view,
        float* __restrict__ out, const int* __restrict__ bev_side_p) {
    __shared__ int   win[CELLS_];      // 44.8 KB
    __shared__ float sV[4][4];
    __shared__ float sE2[4];
    __shared__ float sP[3][4];

    const int m   = blockIdx.x;        // camera index in [0, 96)
    const int b   = m / N_;
    const int rlo = blockIdx.y * HALF_;
    const int t   = threadIdx.x;

    if (t == 0) {
        float Vi[16];
        inv4(&view[b * 16], Vi);
        for (int i = 0; i < 4; ++i)
            for (int j = 0; j < 4; ++j) sV[i][j] = Vi[i * 4 + j];
    } else if (t == 64) {
        float E2[4], PFC[3][4];
        cam_mats(&extr[m * 16], &intr[m * 9], E2, PFC);
        for (int j = 0; j < 4; ++j) sE2[j] = E2[j];
        for (int i = 0; i < 3; ++i)
            for (int j = 0; j < 4; ++j) sP[i][j] = PFC[i][j];
    }
    for (int i = t; i < CELLS_; i += THREADS_) win[i] = -1;
    __syncthreads();

    // ---- Phase A: scatter (LDS atomicMax) ----
    const float4* pcb = pc + (size_t)b * P_;
    for (int p = t; p < P_; p += THREADS_) {
        float4 pt = pcb[p];
        float lx = rdot(sV[0], pt.x, pt.y, pt.z);
        float ly = rdot(sV[1], pt.x, pt.y, pt.z);
        float lz = rdot(sV[2], pt.x, pt.y, pt.z);
        float px = rdot(sP[0], lx, ly, lz);
        float py = rdot(sP[1], lx, ly, lz);
        float pz = rdot(sP[2], lx, ly, lz);
        float denom = fmaxf(pz, 1e-6f);
        float x_ = px / denom;
        float y_ = py / denom;
        int ym = (int)fminf(fmaxf(y_, 0.0f), (float)(H_ - 1));
        int xm = (int)fminf(fmaxf(x_, 0.0f), (float)(W_ - 1));
        int rr = ym - rlo;
        if ((unsigned)rr < (unsigned)HALF_)
            atomicMax(&win[rr * W_ + xm], p);
    }
    __syncthreads();

    // ---- Phase B: finalize this block's rows ----
    const float bev_half = (float)bev_side_p[0] * 0.5f;   // 100.0
    const float clip_hi  = bev_half - 1.0f;               // 99.0
    const int base0 = (m * 2) * HW_ + rlo * W_;
    for (int r = t; r < CELLS_; r += THREADS_) {
        int w = win[r];
        float depth = 0.0f, iluv = 0.0f;
        if (w >= 0) {
            float4 pt = pcb[w];
            float lx = rdot(sV[0], pt.x, pt.y, pt.z);
            float ly = rdot(sV[1], pt.x, pt.y, pt.z);
            float lz = rdot(sV[2], pt.x, pt.y, pt.z);
            float z  = rdot(sE2,   lx, ly, lz);
            float px = rdot(sP[0], lx, ly, lz);
            float py = rdot(sP[1], lx, ly, lz);
            float pz = rdot(sP[2], lx, ly, lz);
            float denom = fmaxf(pz, 1e-6f);
            float x_ = px / denom;
            float y_ = py / denom;
            bool valid = (x_ > -0.5f) && (x_ < (float)W_ - 0.5f) &&
                         (y_ > -0.5f) && (y_ < (float)H_ - 0.5f) && (z > 0.0f);
            if (valid) {
                float d = fminf(fmaxf(pz, 0.0f), clip_hi);     // clip(normalizer,0,99)
                depth = d / bev_half;                           // /100
                float vi = fminf(fmaxf(pt.w, 0.0f), 255.0f);    // clip(ilu,0,255)
                iluv = log1pf(vi) / 5.545177444479562f;         // /log(256) as f32
            }
        }
        out[base0 + r]       = depth;
        out[base0 + HW_ + r] = iluv;
    }
}

// ---------- launch ----------

extern "C" void kernel_launch(void* const* d_in, const int* in_sizes, int n_in,
                              void* d_out, int out_size, void* d_ws, size_t ws_size,
                              hipStream_t stream) {
    const float4* pc  = (const float4*)d_in[0];
    const float* extr = (const float*)d_in[1];
    const float* intr = (const float*)d_in[2];
    const float* view = (const float*)d_in[3];
    const int*   bev  = (const int*)d_in[4];
    float* out = (float*)d_out;

    dim3 grid(BSN_, H_ / HALF_);       // 96 x 2 = 192 blocks
    k_lidar_fused<<<grid, dim3(THREADS_), 0, stream>>>(pc, extr, intr, view, out, bev);
}

// Round 3
// 48.977 us; speedup vs baseline: 26.9183x; 1.4128x over previous
//
#include <hip/hip_runtime.h>
#include <math.h>

#define B_    16
#define N_    6
#define P_    70000
#define H_    112
#define W_    200
#define HW_   (H_ * W_)
#define BSN_  (B_ * N_)
#define HALF_ 56                      // rows per block (H_/2)
#define CELLS_ (HALF_ * W_)           // 11200 cells, 44.8 KB LDS
#define THREADS_ 1024

// ---------- shared math helpers (identical codegen everywhere) ----------

// dot of matrix row r[0..3] with [x,y,z,1], ascending-j fma chain (mirrors
// XLA's sequential reduction for einsum('mij,mpj->mpi'))
__device__ __forceinline__ float rdot(const float r[4], float x, float y, float z) {
    float s = r[0] * x;
    s = fmaf(r[1], y, s);
    s = fmaf(r[2], z, s);
    s = s + r[3];
    return s;
}

// general 4x4 inverse via adjugate (matches jnp.linalg.inv bit-for-bit on
// the setup's view matrices — verified absmax 0.0 in rounds 1-2)
__device__ __forceinline__ void inv4(const float* m, float* o) {
    float inv[16];
    inv[0]  =  m[5]*m[10]*m[15] - m[5]*m[11]*m[14] - m[9]*m[6]*m[15] + m[9]*m[7]*m[14] + m[13]*m[6]*m[11] - m[13]*m[7]*m[10];
    inv[4]  = -m[4]*m[10]*m[15] + m[4]*m[11]*m[14] + m[8]*m[6]*m[15] - m[8]*m[7]*m[14] - m[12]*m[6]*m[11] + m[12]*m[7]*m[10];
    inv[8]  =  m[4]*m[9]*m[15]  - m[4]*m[11]*m[13] - m[8]*m[5]*m[15] + m[8]*m[7]*m[13] + m[12]*m[5]*m[11] - m[12]*m[7]*m[9];
    inv[12] = -m[4]*m[9]*m[14]  + m[4]*m[10]*m[13] + m[8]*m[5]*m[14] - m[8]*m[6]*m[13] - m[12]*m[5]*m[10] + m[12]*m[6]*m[9];
    inv[1]  = -m[1]*m[10]*m[15] + m[1]*m[11]*m[14] + m[9]*m[2]*m[15] - m[9]*m[3]*m[14] - m[13]*m[2]*m[11] + m[13]*m[3]*m[10];
    inv[5]  =  m[0]*m[10]*m[15] - m[0]*m[11]*m[14] - m[8]*m[2]*m[15] + m[8]*m[3]*m[14] + m[12]*m[2]*m[11] - m[12]*m[3]*m[10];
    inv[9]  = -m[0]*m[9]*m[15]  + m[0]*m[11]*m[13] + m[8]*m[1]*m[15] - m[8]*m[3]*m[13] - m[12]*m[1]*m[11] + m[12]*m[3]*m[9];
    inv[13] =  m[0]*m[9]*m[14]  - m[0]*m[10]*m[13] - m[8]*m[1]*m[14] + m[8]*m[2]*m[13] + m[12]*m[1]*m[10] - m[12]*m[2]*m[9];
    inv[2]  =  m[1]*m[6]*m[15]  - m[1]*m[7]*m[14]  - m[5]*m[2]*m[15] + m[5]*m[3]*m[14] + m[13]*m[2]*m[7]  - m[13]*m[3]*m[6];
    inv[6]  = -m[0]*m[6]*m[15]  + m[0]*m[7]*m[14]  + m[4]*m[2]*m[15] - m[4]*m[3]*m[14] - m[12]*m[2]*m[7]  + m[12]*m[3]*m[6];
    inv[10] =  m[0]*m[5]*m[15]  - m[0]*m[7]*m[13]  - m[4]*m[1]*m[15] + m[4]*m[3]*m[13] + m[12]*m[1]*m[7]  - m[12]*m[3]*m[5];
    inv[14] = -m[0]*m[5]*m[14]  + m[0]*m[6]*m[13]  + m[4]*m[1]*m[14] - m[4]*m[2]*m[13] - m[12]*m[1]*m[6]  + m[12]*m[2]*m[5];
    inv[3]  = -m[1]*m[6]*m[11]  + m[1]*m[7]*m[10]  + m[5]*m[2]*m[11] - m[5]*m[3]*m[10] - m[9]*m[2]*m[7]   + m[9]*m[3]*m[6];
    inv[7]  =  m[0]*m[6]*m[11]  - m[0]*m[7]*m[10]  - m[4]*m[2]*m[11] + m[4]*m[3]*m[10] + m[8]*m[2]*m[7]   - m[8]*m[3]*m[6];
    inv[11] = -m[0]*m[5]*m[11]  + m[0]*m[7]*m[9]   + m[4]*m[1]*m[11] - m[4]*m[3]*m[9]  - m[8]*m[1]*m[7]   + m[8]*m[3]*m[5];
    inv[15] =  m[0]*m[5]*m[10]  - m[0]*m[6]*m[9]   - m[4]*m[1]*m[10] + m[4]*m[2]*m[9]  + m[8]*m[1]*m[6]   - m[8]*m[2]*m[5];
    float det = m[0]*inv[0] + m[1]*inv[4] + m[2]*inv[8] + m[3]*inv[12];
    float rdet = 1.0f / det;
    for (int i = 0; i < 16; ++i) o[i] = inv[i] * rdet;
}

// Per-camera: Einv (rigid inverse) and PFC = scale_intrinsics4(K) @ Einv.
__device__ __forceinline__ void cam_mats(const float* Ein, const float* Kin,
                                         float E2[4], float PFC[3][4]) {
    float Einv[4][4];
    for (int i = 0; i < 3; ++i)
        for (int j = 0; j < 3; ++j)
            Einv[i][j] = Ein[j * 4 + i];          // R^T
    for (int i = 0; i < 3; ++i) {                  // -(R^T t), asc-j fma
        float s = Ein[0 * 4 + i] * Ein[0 * 4 + 3];
        s = fmaf(Ein[1 * 4 + i], Ein[1 * 4 + 3], s);
        s = fmaf(Ein[2 * 4 + i], Ein[2 * 4 + 3], s);
        Einv[i][3] = -s;
    }
    Einv[3][0] = Ein[12]; Einv[3][1] = Ein[13];
    Einv[3][2] = Ein[14]; Einv[3][3] = Ein[15];

    float K4[4][4] = {};
    K4[0][0] = Kin[0] * 0.25f;  K4[0][2] = Kin[2] * 0.25f;
    K4[1][1] = Kin[4] * 0.25f;  K4[1][2] = Kin[5] * 0.25f;
    K4[2][2] = 1.0f;            K4[3][3] = 1.0f;

    for (int i = 0; i < 3; ++i)
        for (int j = 0; j < 4; ++j) {
            float s = K4[i][0] * Einv[0][j];
            s = fmaf(K4[i][1], Einv[1][j], s);
            s = fmaf(K4[i][2], Einv[2][j], s);
            s = fmaf(K4[i][3], Einv[3][j], s);
            PFC[i][j] = s;
        }
    for (int j = 0; j < 4; ++j) E2[j] = Einv[2][j];
}

// ---------- fused kernel: one block per (camera m, row-half) ----------
// Phase A: LDS winner grid (max point index wins == XLA last-write-wins),
//          with the 4 grid-corner cells register-cached per lane (behind-
//          camera points all clip there -> would serialize LDS atomics).
// Phase B: recompute winning point per cell and emit depth+ilu channels.

__global__ __launch_bounds__(THREADS_) void k_lidar_fused(
        const float4* __restrict__ pc, const float* __restrict__ extr,
        const float* __restrict__ intr, const float* __restrict__ view,
        float* __restrict__ out, const int* __restrict__ bev_side_p) {
    __shared__ int   win[CELLS_];      // 44.8 KB
    __shared__ float sV[4][4];
    __shared__ float sE2[4];
    __shared__ float sP[3][4];

    // XCD-aware swizzle: dispatch round-robins blocks over 8 XCDs (i%8).
    // Co-locate all 12 blocks (6 cams x 2 halves) of one batch on one XCD
    // so the batch's 1.12 MB of points stays L2-resident (2 batches/XCD).
    const int i    = blockIdx.x;       // 0..191
    const int xcd  = i & 7;
    const int s    = i >> 3;           // 0..23
    const int b    = xcd + 8 * (s >= 12 ? 1 : 0);
    const int c12  = s % 12;
    const int m    = b * N_ + (c12 >> 1);
    const int rlo  = (c12 & 1) * HALF_;
    const int t    = threadIdx.x;

    if (t == 0) {
        float Vi[16];
        inv4(&view[b * 16], Vi);
        for (int ii = 0; ii < 4; ++ii)
            for (int j = 0; j < 4; ++j) sV[ii][j] = Vi[ii * 4 + j];
    } else if (t == 64) {
        float E2[4], PFC[3][4];
        cam_mats(&extr[m * 16], &intr[m * 9], E2, PFC);
        for (int j = 0; j < 4; ++j) sE2[j] = E2[j];
        for (int ii = 0; ii < 3; ++ii)
            for (int j = 0; j < 4; ++j) sP[ii][j] = PFC[ii][j];
    }
    for (int k = t; k < CELLS_; k += THREADS_) win[k] = -1;
    __syncthreads();

    // ---- Phase A: scatter (LDS atomicMax; corners in registers) ----
    const float4* pcb = pc + (size_t)b * P_;
    int c0 = -1, c1 = -1, c2 = -1, c3 = -1;   // max-p for grid corners
    for (int p = t; p < P_; p += THREADS_) {
        float4 pt = pcb[p];
        float lx = rdot(sV[0], pt.x, pt.y, pt.z);
        float ly = rdot(sV[1], pt.x, pt.y, pt.z);
        float lz = rdot(sV[2], pt.x, pt.y, pt.z);
        float px = rdot(sP[0], lx, ly, lz);
        float py = rdot(sP[1], lx, ly, lz);
        float pz = rdot(sP[2], lx, ly, lz);
        float denom = fmaxf(pz, 1e-6f);
        float x_ = px / denom;
        float y_ = py / denom;
        int ym = (int)fminf(fmaxf(y_, 0.0f), (float)(H_ - 1));
        int xm = (int)fminf(fmaxf(x_, 0.0f), (float)(W_ - 1));
        bool is_c = (xm == 0 || xm == W_ - 1) && (ym == 0 || ym == H_ - 1);
        int code = ((ym != 0) << 1) | (xm != 0);
        // p is strictly increasing per lane -> assign is max
        c0 = (is_c && code == 0) ? p : c0;
        c1 = (is_c && code == 1) ? p : c1;
        c2 = (is_c && code == 2) ? p : c2;
        c3 = (is_c && code == 3) ? p : c3;
        int rr = ym - rlo;
        if (!is_c && (unsigned)rr < (unsigned)HALF_)
            atomicMax(&win[rr * W_ + xm], p);
    }
    // wave-reduce corner maxima, then one atomic per wave per in-slab corner
    for (int d = 32; d; d >>= 1) {
        c0 = max(c0, __shfl_xor(c0, d));
        c1 = max(c1, __shfl_xor(c1, d));
        c2 = max(c2, __shfl_xor(c2, d));
        c3 = max(c3, __shfl_xor(c3, d));
    }
    if ((t & 63) == 0) {
        if (rlo == 0) {                               // rows 0..55: corners (0,0),(0,199)
            if (c0 >= 0) atomicMax(&win[0 * W_ + 0],        c0);
            if (c1 >= 0) atomicMax(&win[0 * W_ + (W_ - 1)], c1);
        } else {                                      // rows 56..111: corners (111,0),(111,199)
            if (c2 >= 0) atomicMax(&win[(H_ - 1 - rlo) * W_ + 0],        c2);
            if (c3 >= 0) atomicMax(&win[(H_ - 1 - rlo) * W_ + (W_ - 1)], c3);
        }
    }
    __syncthreads();

    // ---- Phase B: finalize this block's rows ----
    const float bev_half = (float)bev_side_p[0] * 0.5f;   // 100.0
    const float clip_hi  = bev_half - 1.0f;               // 99.0
    const int base0 = (m * 2) * HW_ + rlo * W_;
    for (int r = t; r < CELLS_; r += THREADS_) {
        int w = win[r];
        float depth = 0.0f, iluv = 0.0f;
        if (w >= 0) {
            float4 pt = pcb[w];
            float lx = rdot(sV[0], pt.x, pt.y, pt.z);
            float ly = rdot(sV[1], pt.x, pt.y, pt.z);
            float lz = rdot(sV[2], pt.x, pt.y, pt.z);
            float z  = rdot(sE2,   lx, ly, lz);
            float px = rdot(sP[0], lx, ly, lz);
            float py = rdot(sP[1], lx, ly, lz);
            float pz = rdot(sP[2], lx, ly, lz);
            float denom = fmaxf(pz, 1e-6f);
            float x_ = px / denom;
            float y_ = py / denom;
            bool valid = (x_ > -0.5f) && (x_ < (float)W_ - 0.5f) &&
                         (y_ > -0.5f) && (y_ < (float)H_ - 0.5f) && (z > 0.0f);
            if (valid) {
                float d = fminf(fmaxf(pz, 0.0f), clip_hi);     // clip(normalizer,0,99)
                depth = d / bev_half;                           // /100
                float vi = fminf(fmaxf(pt.w, 0.0f), 255.0f);    // clip(ilu,0,255)
                iluv = log1pf(vi) / 5.545177444479562f;         // /log(256) as f32
            }
        }
        out[base0 + r]       = depth;
        out[base0 + HW_ + r] = iluv;
    }
}

// ---------- launch ----------

extern "C" void kernel_launch(void* const* d_in, const int* in_sizes, int n_in,
                              void* d_out, int out_size, void* d_ws, size_t ws_size,
                              hipStream_t stream) {
    const float4* pc  = (const float4*)d_in[0];
    const float* extr = (const float*)d_in[1];
    const float* intr = (const float*)d_in[2];
    const float* view = (const float*)d_in[3];
    const int*   bev  = (const int*)d_in[4];
    float* out = (float*)d_out;

    k_lidar_fused<<<dim3(BSN_ * 2), dim3(THREADS_), 0, stream>>>(
        pc, extr, intr, view, out, bev);
}